// Round 4
// baseline (95.160 us; speedup 1.0000x reference)
//
#include <hip/hip_runtime.h>
#include <math.h>

#define N_OCT  32
#define N_SMP  32768
#define N_PAIR 64          // B*E = 4*16
#define BPP    32          // blocks per pair: 1024 samples/block, 4/thread

// ---------------------------------------------------------------------------
// R10: single kernel via per-pair tail-block reduction (no grid sync, no
// spinning, no release fences).
//   - R8 lesson: grid-wide sync = ~65 us. R4 lesson: per-block __threadfence
//     (buffer_wbl2, full L2 writeback) = ~420 us. So: cross-XCD visibility is
//     done PER-STORE with relaxed agent-scope atomic stores (bypass the
//     non-coherent per-XCD L2 to the device-coherent point), ordered before a
//     device-scope atomicAdd by a per-wave s_waitcnt vmcnt(0). Zero cache
//     maintenance ops.
//   - Per-pair counter lives in the poisoned d_ws (fill is UNCONDITIONAL per
//     R9 -> using ws is free). Poison baseline P is read from an untouched ws
//     offset; tail condition old == P+31 (unsigned wrap-safe); tail restores
//     the counter with atomicSub(32) so even a skipped re-poison is safe.
//     No spin anywhere -> no deadlock possible; a broken protocol fails LOUD
//     (unnormalized output).
//   - The 32nd-arriving block of each pair normalizes the pair's 32768
//     samples (reads are fresh: those lines were never cached locally, and
//     kernel-boundary invalidation cleared the out-fill's copies). Tail work
//     overlaps other pairs' osc compute.
//   - osc body unchanged (active-octave truncation, 4 FMA chains, exact
//     sequential-cumsum prologue) -> bit-identical output to R7.
// ---------------------------------------------------------------------------
__global__ __launch_bounds__(256) void f0res_osc(
    const float* __restrict__ f0_in,
    const float* __restrict__ dec_in,
    const float* __restrict__ fs_in,
    float* __restrict__ out,
    unsigned int* __restrict__ ws)
{
    __shared__ __align__(16) float sw[N_OCT];
    __shared__ __align__(16) float sa[N_OCT];
    __shared__ int s_ng;
    __shared__ unsigned int s_P;
    __shared__ float wm[4];
    __shared__ int s_last;
    __shared__ float s_inv;

    const int pair = blockIdx.x >> 5;
    const int blk  = blockIdx.x & (BPP - 1);
    const int tid  = threadIdx.x;

    unsigned int* cnt   = ws;                          // [64] u32 counters
    float*        bmax  = (float*)(ws + 256);          // +1KB: [64][32] floats
    const unsigned int* probe = ws + (1u << 18);       // +1MB: untouched poison

    if (tid == 0) s_P = probe[0];                      // per-iteration baseline

    // ---- in-block setup (lanes 0-31 of wave 0) ----
    if (tid < N_OCT) {
        const float minf   = (float)(20.0 / 11025.0);
        const float frange = (float)(3000.0 / 11025.0 - 20.0 / 11025.0);
        const float pif    = 3.14159265358979323846f;
        const float INV2PI = 0.15915494309189535f;

        float f0 = fabsf(f0_in[pair]);
        float fs = fs_in[pair];
        float x  = dec_in[pair];

        float s1 = 1.0f / (1.0f + expf(-x));      // double sigmoid (ref quirk)
        float s2 = 1.0f / (1.0f + expf(-s1));
        float d  = 0.01f + s2 * (float)(0.99 * 0.99);
        float ld = logf(d + 1e-12f);
        float f0p = (minf + f0 * frange) * pif;

        // sequential fp32 cumsums — bit-match the reference rounding order
        float fac = 0.0f, acl = 0.0f, myfac = 0.0f, myacl = 0.0f;
#pragma unroll
        for (int o = 0; o < N_OCT; ++o) {
            fac += fs;
            acl += ld;
            if (o == tid) { myfac = fac; myacl = acl; }
        }
        float f0s = f0p * myfac;
        const bool act = (f0s < 1.0f);            // monotone -> prefix mask
        sw[tid] = act ? f0s * INV2PI : 0.0f;      // revolutions; sin(0)=0
        sa[tid] = expf(myacl);                    // d^(o+1)

        unsigned long long bal = __ballot(act);   // lanes 32-63 inactive -> 0
        if (tid == 0) s_ng = (__popcll(bal) + 3) >> 2;   // active float4 groups
    }
    __syncthreads();

    const int ng = s_ng;                          // uniform per block

    const int   s0 = (blk << 10) + tid;           // samples s0 + {0,256,512,768}
    const float t0 = (float)(s0 + 1);             // t = s+1, exact in fp32
    const float t1 = (float)(s0 + 257);
    const float t2 = (float)(s0 + 513);
    const float t3 = (float)(s0 + 769);

    float acc0 = 0.0f, acc1 = 0.0f, acc2 = 0.0f, acc3 = 0.0f;

    const float4* w4 = (const float4*)sw;
    const float4* a4 = (const float4*)sa;
    for (int i = 0; i < ng; ++i) {
        const float4 wv = w4[i];                  // ds_read_b128 broadcast
        const float4 av = a4[i];
        const float wr[4] = { wv.x, wv.y, wv.z, wv.w };
        const float ar[4] = { av.x, av.y, av.z, av.w };
#pragma unroll
        for (int j = 0; j < 4; ++j) {
            const float w = wr[j], a = ar[j];
            acc0 = fmaf(a, __builtin_amdgcn_sinf(__builtin_amdgcn_fractf(w * t0)), acc0);
            acc1 = fmaf(a, __builtin_amdgcn_sinf(__builtin_amdgcn_fractf(w * t1)), acc1);
            acc2 = fmaf(a, __builtin_amdgcn_sinf(__builtin_amdgcn_fractf(w * t2)), acc2);
            acc3 = fmaf(a, __builtin_amdgcn_sinf(__builtin_amdgcn_fractf(w * t3)), acc3);
        }
    }

    // ---- agent-scope (device-coherent) stores: visible cross-XCD once
    //      vmcnt retires, no fence needed ----
    float* op = out + pair * N_SMP + s0;
    __hip_atomic_store(op + 0,   acc0, __ATOMIC_RELAXED, __HIP_MEMORY_SCOPE_AGENT);
    __hip_atomic_store(op + 256, acc1, __ATOMIC_RELAXED, __HIP_MEMORY_SCOPE_AGENT);
    __hip_atomic_store(op + 512, acc2, __ATOMIC_RELAXED, __HIP_MEMORY_SCOPE_AGENT);
    __hip_atomic_store(op + 768, acc3, __ATOMIC_RELAXED, __HIP_MEMORY_SCOPE_AGENT);

    // ---- block max ----
    float av_ = fmaxf(fmaxf(fabsf(acc0), fabsf(acc1)),
                      fmaxf(fabsf(acc2), fabsf(acc3)));
#pragma unroll
    for (int m = 32; m >= 1; m >>= 1)
        av_ = fmaxf(av_, __shfl_xor(av_, m, 64));
    if ((tid & 63) == 0) wm[tid >> 6] = av_;

    // every wave drains its own stores before the barrier (release half)
    asm volatile("s_waitcnt vmcnt(0)" ::: "memory");
    __syncthreads();

    if (tid == 0) {
        float bm = fmaxf(fmaxf(wm[0], wm[1]), fmaxf(wm[2], wm[3]));
        __hip_atomic_store(&bmax[(pair << 5) + blk], bm,
                           __ATOMIC_RELAXED, __HIP_MEMORY_SCOPE_AGENT);
        asm volatile("s_waitcnt vmcnt(0)" ::: "memory");
        unsigned int old = atomicAdd(&cnt[pair], 1u);   // device-scope RMW
        s_last = (old == s_P + 31u);                    // unsigned wrap-safe
    }
    __syncthreads();

    if (!s_last) return;                                // non-tail blocks exit

    // ================= tail: normalize the whole pair =================
    asm volatile("" ::: "memory");                      // no load hoisting

    if (tid < 64) {
        float v = (tid < 32) ? bmax[(pair << 5) + tid] : 0.0f;
#pragma unroll
        for (int m = 16; m >= 1; m >>= 1)
            v = fmaxf(v, __shfl_xor(v, m, 64));
        if (tid == 0) s_inv = 1.0f / (v + 1e-8f);
    }
    __syncthreads();
    const float inv = s_inv;

    float4* o4 = (float4*)(out + pair * N_SMP);         // 8192 float4
#pragma unroll
    for (int g = 0; g < 4; ++g) {                       // 8 loads in flight
        float4 v[8];
#pragma unroll
        for (int j = 0; j < 8; ++j)
            v[j] = o4[tid + (((g << 3) + j) << 8)];
#pragma unroll
        for (int j = 0; j < 8; ++j) {
            v[j].x *= inv; v[j].y *= inv; v[j].z *= inv; v[j].w *= inv;
            o4[tid + (((g << 3) + j) << 8)] = v[j];
        }
    }

    if (tid == 0) atomicAdd(&cnt[pair], (unsigned int)-32);  // self-restore
}

extern "C" void kernel_launch(void* const* d_in, const int* in_sizes, int n_in,
                              void* d_out, int out_size, void* d_ws, size_t ws_size,
                              hipStream_t stream) {
    const float* f0  = (const float*)d_in[0];
    const float* dec = (const float*)d_in[1];
    const float* fs  = (const float*)d_in[2];
    float* out = (float*)d_out;
    unsigned int* ws = (unsigned int*)d_ws;

    f0res_osc<<<N_PAIR * BPP, 256, 0, stream>>>(f0, dec, fs, out, ws);
}